// Round 1
// baseline (2973.427 us; speedup 1.0000x reference)
//
#include <hip/hip_runtime.h>
#include <cstdint>
#include <cstddef>

// RNNDecoder: B=32, T=64, S=400, V=50257, DW=DM=DE=512, DK=64, POOL=2
// Strategy: per-step K1 (bf16 MFMA GEMMs: gx, gh, readout(t-1), copy_gate(t-1))
//           per-step K2 (per-batch attention, 4 blocks/batch, fp32 math)
// State fp32 masters; bf16 only as MFMA inputs (2e-2 abs tolerance).

#define PAD_ID_C 50256

typedef float f32x4 __attribute__((ext_vector_type(4)));
typedef short bf16x8 __attribute__((ext_vector_type(8)));

__device__ __forceinline__ unsigned short f2bf(float x){
  union { float f; unsigned u; } v; v.f = x;
  unsigned r = (v.u + 0x7FFFu + ((v.u >> 16) & 1u)) >> 16;
  return (unsigned short)r;
}
__device__ __forceinline__ float bf2f(unsigned short h){
  union { unsigned u; float f; } v; v.u = ((unsigned)h) << 16; return v.f;
}
__device__ __forceinline__ float sigm_(float x){ return 1.f/(1.f+__expf(-x)); }
__device__ __forceinline__ float tanh_(float x){ float e=__expf(2.f*x); return 1.f - 2.f/(e+1.f); }

// packed A-activation index for [32][512] src -> tiles (mt,kt,lane,8)
__device__ __forceinline__ int pkidx(int b, int d){
  return ((((b>>4)*16) + (d>>5))*64 + (((d>>3)&3)*16) + (b&15))*8 + (d&7);
}

// ---------------- init kernels ----------------

// Pack weight W[K][N] (row-major f32) into MFMA B-fragment layout:
// pk[((nt*(K/32)+kt)*64+lane)*8+j] = bf16(W[(kt*32+(lane>>4)*8+j)*N + nt*16+(lane&15)])
__global__ void k_pack(const float* __restrict__ W, unsigned short* __restrict__ pk, int N, int K){
  int ktc = K >> 5;
  int gid = blockIdx.x*256 + threadIdx.x;
  int total = (N>>4)*ktc*64;
  if (gid >= total) return;
  int lane = gid & 63;
  int rem = gid >> 6;
  int kt = rem % ktc, nt = rem / ktc;
  int k0 = kt*32 + (lane>>4)*8;
  int n  = nt*16 + (lane&15);
  #pragma unroll
  for (int j=0;j<8;j++) pk[gid*8+j] = f2bf(W[(k0+j)*N + n]);
}

__global__ void k_misc(const float* __restrict__ Wq, unsigned short* __restrict__ wq_bf,
                       float* __restrict__ cov0){
  int idx = blockIdx.x*256 + threadIdx.x;
  if (idx < 512*64) wq_bf[idx] = f2bf(Wq[idx]);
  else if (idx < 512*64 + 32*400) cov0[idx - 512*64] = 0.f;
}

// gather embeddings -> packed bf16 [t][mt][kt][lane][8]
__global__ void k_emb(const int* __restrict__ tgt, const float* __restrict__ word_emb,
                      unsigned short* __restrict__ emb_pk){
  int bid = blockIdx.x;           // t*32+b
  int t = bid >> 5, b = bid & 31;
  int token = tgt[b*64 + t];
  const float* src = word_emb + (size_t)token*512;
  for (int d = threadIdx.x; d < 512; d += 256){
    int idx = (((t*2 + (b>>4))*16 + (d>>5))*64 + ((d>>3)&3)*16 + (b&15))*8 + (d&7);
    emb_pk[idx] = f2bf(src[d]);
  }
}

__global__ void k_encbf(const float* __restrict__ enc, unsigned short* __restrict__ enc_bf){
  int idx = blockIdx.x*256 + threadIdx.x;
  if (idx < 32*400*512) enc_bf[idx] = f2bf(enc[idx]);
}

// pre_t[b][k][s] = bf16( sum_d enc[b,s,d]*Wc[d,k] )
__global__ void k_pre(const float* __restrict__ enc, const float* __restrict__ Wc,
                      unsigned short* __restrict__ pre_t){
  int bs = blockIdx.x;            // b*400+s
  int b = bs / 400, s = bs % 400;
  int k = threadIdx.x;            // 64 threads
  const float* e = enc + (size_t)bs*512;
  float acc = 0.f;
  for (int d=0; d<512; d++) acc += e[d]*Wc[d*64+k];
  pre_t[(b*64+k)*400 + s] = f2bf(acc);
}

// h0 = tanh(hidden@W_init + b_init); ctx=0
__global__ void k_h0(const float* __restrict__ hidden, const float* __restrict__ W_init,
                     const float* __restrict__ b_init,
                     float* __restrict__ h_f32, unsigned short* __restrict__ h_pk,
                     float* __restrict__ ctx_f32, unsigned short* __restrict__ ctx_pk){
  int b = blockIdx.x, jj = threadIdx.x;   // 32 x 512
  const float* hv = hidden + b*512;
  float acc = 0.f;
  for (int d=0; d<512; d++) acc += hv[d]*W_init[d*512+jj];
  float h = tanh_(acc + b_init[jj]);
  h_f32[b*512+jj] = h;
  h_pk[pkidx(b,jj)] = f2bf(h);
  ctx_f32[b*512+jj] = 0.f;
  ctx_pk[b*512+jj] = 0;   // zeros in any layout are zeros
}

// ---------------- per-step K1: GEMMs via MFMA ----------------
// waves: [0,192) gx  (mt=w/96, nt=w%96, K=1024: emb(t)|ctx)
//        [192,384) gh (K=512: h)
//        [384,448) readout(t-1) (mt=i/32, nt=i%32, K=1536: emb(t-1)|h|ctx)
//        [448,480) copy_gate(t-1) wave-jobs
__global__ __launch_bounds__(256,1) void k_gemm(
    const unsigned short* __restrict__ emb_pk, const unsigned short* __restrict__ h_pk,
    const unsigned short* __restrict__ ctx_pk,
    const unsigned short* __restrict__ wx_pk, const unsigned short* __restrict__ wh_pk,
    const unsigned short* __restrict__ wr_pk,
    float* __restrict__ gxbuf, float* __restrict__ ghbuf, float* __restrict__ robuf,
    const float* __restrict__ h_f32, const float* __restrict__ ctx_f32,
    const float* __restrict__ W_copy, const float* __restrict__ b_copy,
    float* __restrict__ out_gate, int t)
{
  int wv = blockIdx.x*4 + (threadIdx.x>>6);
  int lane = threadIdx.x & 63;
  if (wv < 384){
    if (t >= 64) return;
    int isGh = (wv >= 192);
    int ww = isGh ? wv-192 : wv;
    int nt = ww % 96, mt = ww / 96;
    f32x4 acc = {0.f,0.f,0.f,0.f};
    if (!isGh){
      const bf16x8* wp = (const bf16x8*)wx_pk + (size_t)(nt*32)*64 + lane;
      const bf16x8* ae = (const bf16x8*)emb_pk + (size_t)((t*2+mt)*16)*64 + lane;
      const bf16x8* ac = (const bf16x8*)ctx_pk + (size_t)(mt*16)*64 + lane;
      #pragma unroll
      for (int kt=0; kt<16; kt++)
        acc = __builtin_amdgcn_mfma_f32_16x16x32_bf16(ae[kt*64], wp[kt*64], acc, 0,0,0);
      #pragma unroll
      for (int kt=0; kt<16; kt++)
        acc = __builtin_amdgcn_mfma_f32_16x16x32_bf16(ac[kt*64], wp[(16+kt)*64], acc, 0,0,0);
      int row = mt*16 + (lane>>4)*4, col = nt*16 + (lane&15);
      #pragma unroll
      for (int i=0;i<4;i++) gxbuf[(row+i)*1536 + col] = acc[i];
    } else {
      const bf16x8* wp = (const bf16x8*)wh_pk + (size_t)(nt*16)*64 + lane;
      const bf16x8* ah = (const bf16x8*)h_pk + (size_t)(mt*16)*64 + lane;
      #pragma unroll
      for (int kt=0; kt<16; kt++)
        acc = __builtin_amdgcn_mfma_f32_16x16x32_bf16(ah[kt*64], wp[kt*64], acc, 0,0,0);
      int row = mt*16 + (lane>>4)*4, col = nt*16 + (lane&15);
      #pragma unroll
      for (int i=0;i<4;i++) ghbuf[(row+i)*1536 + col] = acc[i];
    }
  } else if (wv < 448){
    if (t == 0) return;
    int i = wv - 384;
    int nt = i % 32, mt = i / 32;
    f32x4 acc = {0.f,0.f,0.f,0.f};
    const bf16x8* wp = (const bf16x8*)wr_pk + (size_t)(nt*48)*64 + lane;
    const bf16x8* ae = (const bf16x8*)emb_pk + (size_t)(((t-1)*2+mt)*16)*64 + lane;
    const bf16x8* ah = (const bf16x8*)h_pk + (size_t)(mt*16)*64 + lane;
    const bf16x8* ac = (const bf16x8*)ctx_pk + (size_t)(mt*16)*64 + lane;
    #pragma unroll
    for (int kt=0; kt<16; kt++)
      acc = __builtin_amdgcn_mfma_f32_16x16x32_bf16(ae[kt*64], wp[kt*64], acc, 0,0,0);
    #pragma unroll
    for (int kt=0; kt<16; kt++)
      acc = __builtin_amdgcn_mfma_f32_16x16x32_bf16(ah[kt*64], wp[(16+kt)*64], acc, 0,0,0);
    #pragma unroll
    for (int kt=0; kt<16; kt++)
      acc = __builtin_amdgcn_mfma_f32_16x16x32_bf16(ac[kt*64], wp[(32+kt)*64], acc, 0,0,0);
    int row = mt*16 + (lane>>4)*4, col = nt*16 + (lane&15);
    #pragma unroll
    for (int i=0;i<4;i++) robuf[(row+i)*512 + col] = acc[i];
  } else {
    if (t == 0) return;
    int b = wv - 448;   // copy_gate(t-1) = sigmoid([h,ctx]@W_copy + b_copy)
    float acc = 0.f;
    #pragma unroll
    for (int i=0;i<16;i++){
      int j = i*64 + lane;
      float x = (j < 512) ? h_f32[b*512+j] : ctx_f32[b*512 + (j-512)];
      acc += x * W_copy[j];
    }
    for (int off=32; off>0; off>>=1) acc += __shfl_down(acc, off, 64);
    if (lane == 0) out_gate[b*64 + (t-1)] = sigm_(acc + b_copy[0]);
  }
}

// ---------------- per-step K2: combine + attention ----------------
// grid 128 = b*4+g, 512 threads
__global__ __launch_bounds__(512,1) void k_attn(
    const float* __restrict__ gxbuf, const float* __restrict__ ghbuf,
    const float* __restrict__ robuf,
    const float* __restrict__ bx, const float* __restrict__ bh,
    const float* __restrict__ b_read,
    float* __restrict__ h_f32, unsigned short* __restrict__ h_pk,
    float* __restrict__ ctx_f32, unsigned short* __restrict__ ctx_pk,
    float* __restrict__ cov_base,
    const unsigned short* __restrict__ pre_t, const unsigned short* __restrict__ wq_bf,
    const float* __restrict__ w_cov, const float* __restrict__ v_att,
    const unsigned short* __restrict__ enc_bf, const int* __restrict__ src_seq,
    float* __restrict__ out_pred, float* __restrict__ out_attnlast,
    float* __restrict__ out_ctxf, float* __restrict__ out_copypred,
    float* __restrict__ out_covloss, int t)
{
  int b = blockIdx.x >> 2, g = blockIdx.x & 3;
  int tid = threadIdx.x;
  const float* cov_r = cov_base + (t & 1)*12800;
  float* cov_w = cov_base + ((t+1) & 1)*12800;

  __shared__ float h_s[512];
  __shared__ float hq_part[8][64];
  __shared__ float hq_s[64];
  __shared__ float wv_s[128];
  __shared__ float p_s[400];
  __shared__ float red[512];
  __shared__ float cred[4][128];

  // phase 0: GRU combine -> h(t)
  {
    int jj = tid;
    float gx0 = gxbuf[b*1536+jj], gx1 = gxbuf[b*1536+512+jj], gx2 = gxbuf[b*1536+1024+jj];
    float gh0 = ghbuf[b*1536+jj], gh1 = ghbuf[b*1536+512+jj], gh2 = ghbuf[b*1536+1024+jj];
    float r = sigm_(gx0 + bx[jj]     + gh0 + bh[jj]);
    float z = sigm_(gx1 + bx[512+jj] + gh1 + bh[512+jj]);
    float n = tanh_(gx2 + bx[1024+jj] + r*(gh2 + bh[1024+jj]));
    float hold = h_f32[b*512+jj];
    float hn = (1.f - z)*n + z*hold;
    h_s[jj] = hn;
    if (g == 0){ h_f32[b*512+jj] = hn; h_pk[pkidx(b,jj)] = f2bf(hn); }
  }
  if (tid < 128) wv_s[tid] = (tid < 64) ? w_cov[tid] : v_att[tid-64];
  // phase 0b: maxout of readout(t-1)
  if (t > 0 && g == 0 && tid < 256){
    float r0 = robuf[b*512 + 2*tid]     + b_read[2*tid];
    float r1 = robuf[b*512 + 2*tid + 1] + b_read[2*tid + 1];
    out_pred[((size_t)b*64 + (t-1))*256 + tid] = fmaxf(r0, r1);
  }
  __syncthreads();

  // phase 1: hq = h @ Wq  (64 outputs, 8-way k-split)
  {
    int k = tid & 63, p = tid >> 6;
    float a = 0.f;
    const unsigned short* wq = wq_bf + k;
    for (int d = p*64; d < p*64 + 64; d++) a += h_s[d]*bf2f(wq[d*64]);
    hq_part[p][k] = a;
  }
  __syncthreads();
  if (tid < 64){
    float a = 0.f;
    #pragma unroll
    for (int p=0;p<8;p++) a += hq_part[p][tid];
    hq_s[tid] = a;
  }
  __syncthreads();

  // phase 2: scores + exp (no max-subtraction: |score| < ~1)
  float c_old = 0.f, p_val = 0.f;
  int s = tid;
  if (s < 400){
    c_old = cov_r[b*400+s];
    float a = 0.f;
    const unsigned short* pp = pre_t + (b*64)*400 + s;
    #pragma unroll 4
    for (int k=0;k<64;k++){
      float e = bf2f(pp[k*400]) + hq_s[k] + c_old*wv_s[k];
      a += tanh_(e)*wv_s[64+k];
    }
    p_val = (src_seq[b*400+s] == PAD_ID_C) ? 0.f : __expf(a);
    p_s[s] = p_val;
  }
  red[tid] = (s < 400) ? p_val : 0.f;
  __syncthreads();
  for (int st=256; st>0; st>>=1){ if (tid<st) red[tid]+=red[tid+st]; __syncthreads(); }
  float total = red[0];
  float inv_total = 1.f/total;
  __syncthreads();

  // phase 3: attn, cov update, cov_loss
  float cl = 0.f;
  float inv_t = 1.f/(float)(t < 1 ? 1 : t);
  if (s < 400){
    float attn = p_val*inv_total;
    if (g == 0){
      out_copypred[((size_t)b*64 + t)*400 + s] = attn;
      cov_w[b*400+s] = c_old + attn;
      if (t == 63) out_attnlast[b*400+s] = attn;
    }
    cl = fminf(attn, c_old*inv_t);
  }
  red[tid] = cl;
  __syncthreads();
  for (int st=256; st>0; st>>=1){ if (tid<st) red[tid]+=red[tid+st]; __syncthreads(); }
  if (g == 0 && tid == 0) out_covloss[b*64 + t] = red[0];

  // phase 4: ctx slice (128 d per block, 4-way s-split)
  {
    int d = tid & 127, sp = tid >> 7;
    int dg = g*128 + d;
    float a = 0.f;
    const unsigned short* ep = enc_bf + (size_t)(b*400)*512 + dg;
    for (int ss = sp; ss < 400; ss += 4) a += p_s[ss]*bf2f(ep[(size_t)ss*512]);
    cred[sp][d] = a;
  }
  __syncthreads();
  if (tid < 128){
    float cx = (cred[0][tid]+cred[1][tid]+cred[2][tid]+cred[3][tid])*inv_total;
    int dg = g*128 + tid;
    ctx_f32[b*512+dg] = cx;
    ctx_pk[pkidx(b,dg)] = f2bf(cx);
    if (t == 63) out_ctxf[b*512+dg] = cx;
  }
}

// final maxout for t=63
__global__ void k_fin(const float* __restrict__ robuf, const float* __restrict__ b_read,
                      float* __restrict__ out_pred){
  int b = blockIdx.x, jo = threadIdx.x;  // 32 x 256
  float r0 = robuf[b*512 + 2*jo]     + b_read[2*jo];
  float r1 = robuf[b*512 + 2*jo + 1] + b_read[2*jo + 1];
  out_pred[((size_t)b*64 + 63)*256 + jo] = fmaxf(r0, r1);
}

// ---------------- host ----------------
extern "C" void kernel_launch(void* const* d_in, const int* in_sizes, int n_in,
                              void* d_out, int out_size, void* d_ws, size_t ws_size,
                              hipStream_t stream) {
  const int*   tgt     = (const int*)  d_in[0];
  const int*   src     = (const int*)  d_in[1];
  const float* enc     = (const float*)d_in[2];
  const float* hidden  = (const float*)d_in[3];
  const float* wemb    = (const float*)d_in[4];
  const float* W_init  = (const float*)d_in[5];
  const float* b_init  = (const float*)d_in[6];
  const float* Wx      = (const float*)d_in[7];
  const float* Wh      = (const float*)d_in[8];
  const float* bx      = (const float*)d_in[9];
  const float* bh      = (const float*)d_in[10];
  const float* Wc      = (const float*)d_in[11];
  const float* Wq      = (const float*)d_in[12];
  const float* w_cov   = (const float*)d_in[13];
  const float* v_att   = (const float*)d_in[14];
  const float* W_copy  = (const float*)d_in[15];
  const float* b_copy  = (const float*)d_in[16];
  const float* W_read  = (const float*)d_in[17];
  const float* b_read  = (const float*)d_in[18];

  float* out0 = (float*)d_out;            // pred [32,64,256]
  float* out1 = out0 + 524288;            // attn_last [32,400]
  float* out2 = out0 + 537088;            // ctx_f [32,512]
  float* out3 = out0 + 553472;            // copy_pred [32,64,400]
  float* out4 = out0 + 1372672;           // copy_gate [32,64,1]
  float* out5 = out0 + 1374720;           // coverage_pred [32,64]

  uint8_t* w = (uint8_t*)d_ws;
  unsigned short* emb_pk = (unsigned short*)(w);              // 2,097,152 B
  unsigned short* enc_bf = (unsigned short*)(w + 2097152);    // 13,107,200
  unsigned short* pre_t  = (unsigned short*)(w + 15204352);   // 1,638,400
  unsigned short* wx_pk  = (unsigned short*)(w + 16842752);   // 3,145,728
  unsigned short* wh_pk  = (unsigned short*)(w + 19988480);   // 1,572,864
  unsigned short* wr_pk  = (unsigned short*)(w + 21561344);   // 1,572,864
  unsigned short* wq_bf  = (unsigned short*)(w + 23134208);   // 65,536
  float* gxbuf  = (float*)(w + 23199744);                     // 196,608
  float* ghbuf  = (float*)(w + 23396352);                     // 196,608
  float* robuf  = (float*)(w + 23592960);                     // 65,536
  float* h_f32  = (float*)(w + 23658496);                     // 65,536
  unsigned short* h_pk   = (unsigned short*)(w + 23724032);   // 32,768
  float* ctx_f32 = (float*)(w + 23756800);                    // 65,536
  unsigned short* ctx_pk = (unsigned short*)(w + 23822336);   // 32,768
  float* covb   = (float*)(w + 23855104);                     // 102,400  (2x ping-pong)

  // init
  k_pack<<<768, 256, 0, stream>>>(Wx, wx_pk, 1536, 1024);
  k_pack<<<384, 256, 0, stream>>>(Wh, wh_pk, 1536, 512);
  k_pack<<<384, 256, 0, stream>>>(W_read, wr_pk, 512, 1536);
  k_misc<<<178, 256, 0, stream>>>(Wq, wq_bf, covb);
  k_emb<<<2048, 256, 0, stream>>>(tgt, wemb, emb_pk);
  k_encbf<<<25600, 256, 0, stream>>>(enc, enc_bf);
  k_pre<<<12800, 64, 0, stream>>>(enc, Wc, pre_t);
  k_h0<<<32, 512, 0, stream>>>(hidden, W_init, b_init, h_f32, h_pk, ctx_f32, ctx_pk);

  for (int t = 0; t < 64; t++){
    k_gemm<<<120, 256, 0, stream>>>(emb_pk, h_pk, ctx_pk, wx_pk, wh_pk, wr_pk,
                                    gxbuf, ghbuf, robuf, h_f32, ctx_f32,
                                    W_copy, b_copy, out4, t);
    k_attn<<<128, 512, 0, stream>>>(gxbuf, ghbuf, robuf, bx, bh, b_read,
                                    h_f32, h_pk, ctx_f32, ctx_pk, covb,
                                    pre_t, wq_bf, w_cov, v_att, enc_bf, src,
                                    out0, out1, out2, out3, out5, t);
  }
  // final: readout(63) + copy_gate(63), then maxout(63)
  k_gemm<<<120, 256, 0, stream>>>(emb_pk, h_pk, ctx_pk, wx_pk, wh_pk, wr_pk,
                                  gxbuf, ghbuf, robuf, h_f32, ctx_f32,
                                  W_copy, b_copy, out4, 64);
  k_fin<<<32, 256, 0, stream>>>(robuf, b_read, out0);
}